// Round 17
// baseline (287.808 us; speedup 1.0000x reference)
//
#include <hip/hip_runtime.h>
#include <stdint.h>

#define DM 1024
#define NH 16
#define DKH 64
#define BB 4
#define SS 4096
#define MM (BB*SS)   // 16384

typedef __bf16 bf16x8 __attribute__((ext_vector_type(8)));
typedef float f32x4 __attribute__((ext_vector_type(4)));

__device__ __forceinline__ float bf2f(ushort u) {
  union { uint32_t i; float f; } v; v.i = ((uint32_t)u) << 16; return v.f;
}
__device__ __forceinline__ ushort f2bf(float f) {
  union { float f; uint32_t i; } v; v.f = f;
  uint32_t x = v.i;
  uint32_t r = (x + 0x7fffu + ((x >> 16) & 1u)) >> 16;
  return (ushort)r;
}
__device__ __forceinline__ void unpack8(uint4 u, float* o) {
  o[0] = bf2f((ushort)(u.x & 0xffff)); o[1] = bf2f((ushort)(u.x >> 16));
  o[2] = bf2f((ushort)(u.y & 0xffff)); o[3] = bf2f((ushort)(u.y >> 16));
  o[4] = bf2f((ushort)(u.z & 0xffff)); o[5] = bf2f((ushort)(u.z >> 16));
  o[6] = bf2f((ushort)(u.w & 0xffff)); o[7] = bf2f((ushort)(u.w >> 16));
}
__device__ __forceinline__ void unpack4(uint2 u, float* o) {
  o[0] = bf2f((ushort)(u.x & 0xffff)); o[1] = bf2f((ushort)(u.x >> 16));
  o[2] = bf2f((ushort)(u.y & 0xffff)); o[3] = bf2f((ushort)(u.y >> 16));
}

#define GLL16(g, l) __builtin_amdgcn_global_load_lds( \
    (__attribute__((address_space(1))) void*)(g), \
    (__attribute__((address_space(3))) void*)(l), 16, 0, 0)

// ---------------- fused cast: 4 weight matrices in one launch ----------------
__global__ void cast_w4(const float* __restrict__ s0, const float* __restrict__ s1,
                        const float* __restrict__ s2, const float* __restrict__ s3,
                        ushort* __restrict__ d0, ushort* __restrict__ d1,
                        ushort* __restrict__ d2, ushort* __restrict__ d3) {
  const int which = blockIdx.x >> 10;              // 1024 blocks per tensor
  const int i = ((blockIdx.x & 1023) * 256 + threadIdx.x) * 4;
  const float* src = which == 0 ? s0 : (which == 1 ? s1 : (which == 2 ? s2 : s3));
  ushort* dst = which == 0 ? d0 : (which == 1 ? d1 : (which == 2 ? d2 : d3));
  float4 v = *reinterpret_cast<const float4*>(src + i);
  ushort4 o; o.x = f2bf(v.x); o.y = f2bf(v.y); o.z = f2bf(v.z); o.w = f2bf(v.w);
  *reinterpret_cast<ushort4*>(dst + i) = o;
}

// ---------------- 256x256 counted-vmcnt pipelined bf16 GEMM (bf16 A) ----------------
// R7's proven kernel, used for the final output projection.
template<int MODE>
__global__ __launch_bounds__(512, 2) void gemm8p(
    const ushort* __restrict__ A, const ushort* __restrict__ Bw,
    const float* __restrict__ bias, void* __restrict__ Cout) {
  constexpr int K = DM, N = DM;
  constexpr int NT = K / 32;
  __shared__ ushort smem[4][2][256 * 32];   // 128 KiB
  const int t = threadIdx.x;
  const int lane = t & 63;
  const int w = t >> 6;
  const int id = blockIdx.y * gridDim.x + blockIdx.x;
  const int cpx = (gridDim.x * gridDim.y) >> 3;
  const int swz = (id & 7) * cpx + (id >> 3);
  const int bx = swz % gridDim.x;
  const int by = swz / gridDim.x;
  const int m0 = by * 256, n0 = bx * 256;
  const int wm = w >> 2, wn = w & 3;
  const int fr = lane & 15;
  const int slot = lane >> 4;

  const int gsw = ((t & 3) ^ ((t >> 2) & 3)) * 8;
  const size_t baseA = (size_t)(m0 + (t >> 2)) * K + gsw;
  const size_t baseB = (size_t)(n0 + (t >> 2)) * K + gsw;
  const int ldsoff = w * 512;

  f32x4 acc[8][4] = {};

#define STAGE(tile) { \
    const int _b = (tile) & 3; const size_t _k = (size_t)(tile) * 32; \
    GLL16(A + baseA + _k, &smem[_b][0][ldsoff]); \
    GLL16(A + baseA + (size_t)128 * K + _k, &smem[_b][0][4096 + ldsoff]); \
    GLL16(Bw + baseB + _k, &smem[_b][1][ldsoff]); \
    GLL16(Bw + baseB + (size_t)128 * K + _k, &smem[_b][1][4096 + ldsoff]); }

  STAGE(0); STAGE(1); STAGE(2);
  asm volatile("s_waitcnt vmcnt(8)" ::: "memory");
  __builtin_amdgcn_s_barrier();
  __builtin_amdgcn_sched_barrier(0);

  for (int p = 0; p < NT; ++p) {
    const ushort* At = &smem[p & 3][0][0];
    const ushort* Bt = &smem[p & 3][1][0];
    bf16x8 bfr[4], afr[8];
#pragma unroll
    for (int ni = 0; ni < 4; ++ni) {
      const int row = wn * 64 + ni * 16 + fr;
      bfr[ni] = *reinterpret_cast<const bf16x8*>(Bt + row * 32 + ((slot ^ (fr & 3)) << 3));
    }
#pragma unroll
    for (int mi = 0; mi < 8; ++mi) {
      const int row = wm * 128 + mi * 16 + fr;
      afr[mi] = *reinterpret_cast<const bf16x8*>(At + row * 32 + ((slot ^ (fr & 3)) << 3));
    }
    if (p + 3 < NT) STAGE(p + 3);
    __builtin_amdgcn_s_setprio(1);
#pragma unroll
    for (int mi = 0; mi < 8; ++mi)
#pragma unroll
      for (int ni = 0; ni < 4; ++ni)
        acc[mi][ni] = __builtin_amdgcn_mfma_f32_16x16x32_bf16(afr[mi], bfr[ni], acc[mi][ni], 0, 0, 0);
    __builtin_amdgcn_s_setprio(0);
    if (p < NT - 1) {
      if (p < NT - 3)       asm volatile("s_waitcnt vmcnt(8)" ::: "memory");
      else if (p == NT - 3) asm volatile("s_waitcnt vmcnt(4)" ::: "memory");
      else                  asm volatile("s_waitcnt vmcnt(0)" ::: "memory");
      __builtin_amdgcn_s_barrier();
      __builtin_amdgcn_sched_barrier(0);
    }
  }
#undef STAGE

  const int fq = (lane >> 4) * 4;
  float bv[4];
#pragma unroll
  for (int ni = 0; ni < 4; ++ni) bv[ni] = bias[n0 + wn * 64 + ni * 16 + fr];
#pragma unroll
  for (int mi = 0; mi < 8; ++mi) {
#pragma unroll
    for (int ni = 0; ni < 4; ++ni) {
      const int c = n0 + wn * 64 + ni * 16 + fr;
#pragma unroll
      for (int q = 0; q < 4; ++q) {
        const int r = m0 + wm * 128 + mi * 16 + fq + q;
        float v = acc[mi][ni][q] + bv[ni];
        if constexpr (MODE == 0) v = (v > 0.f) ? (v + 1.f) : __expf(v);
        if constexpr (MODE == 2) {
          reinterpret_cast<float*>(Cout)[(size_t)r * N + c] = v;
        } else {
          reinterpret_cast<ushort*>(Cout)[(size_t)r * N + c] = f2bf(v);
        }
      }
    }
  }
}

// ---------------- fused-cast projection GEMM v7 (sub-phase interleave):
// R10 v3 staging/read paths and vmcnt audit UNCHANGED (depth-3 A fp32 + B
// bf16 via GLL16, read-side cvt_pk, wave tile 64x128, steady vmcnt(6)).
// NEW: each K-tile split into 4 sub-phases {reads + stage-share -> rhythm
// barrier -> setprio 8-MFMA cluster} so waves de-phase and the VMEM-issue
// path stays busy during MFMA (T3 mechanism; barriers are pure rhythm —
// reads hit resident tile p, GLL16s target buffer (p+2)%3, uniform flow).
// Per-tile issue order stays A x4 then B x2 -> vmcnt counts identical.
__global__ __launch_bounds__(512, 2) void gemm8pa(
    const float* __restrict__ Q32, const float* __restrict__ K32,
    const float* __restrict__ V32,
    const ushort* __restrict__ Wq, const ushort* __restrict__ Wk,
    const ushort* __restrict__ Wv,
    const float* __restrict__ bq, const float* __restrict__ bk,
    const float* __restrict__ bv_,
    ushort* __restrict__ Qp, ushort* __restrict__ Kp, ushort* __restrict__ Vp) {
  constexpr int K = DM, N = DM;
  constexpr int NT = K / 32;            // 32
  __shared__ float  smemA[3][256 * 32];   // 96 KiB (fp32 tiles)
  __shared__ ushort smemB[3][256 * 32];   // 48 KiB
  const int bz = blockIdx.z;
  const float*  A32  = bz == 0 ? Q32 : (bz == 1 ? K32 : V32);
  const ushort* Bw   = bz == 0 ? Wq  : (bz == 1 ? Wk  : Wv);
  const float*  bias = bz == 0 ? bq  : (bz == 1 ? bk  : bv_);
  ushort*       Cout = bz == 0 ? Qp  : (bz == 1 ? Kp  : Vp);
  const bool do_elu = (bz != 2);

  const int t = threadIdx.x;
  const int lane = t & 63;
  const int w = t >> 6;
  const int id = blockIdx.y * gridDim.x + blockIdx.x;
  const int cpx = (gridDim.x * gridDim.y) >> 3;
  const int swz = (id & 7) * cpx + (id >> 3);
  const int bx = swz % gridDim.x;
  const int by = swz / gridDim.x;
  const int m0 = by * 256, n0 = bx * 256;
  const int wm = w >> 1, wn = w & 1;      // wave tile: 64 rows x 128 cols
  const int fr = lane & 15;
  const int slot = lane >> 4;

  const int gcolA = (((t & 7) ^ ((t >> 3) & 7)) << 2);
  const size_t baseAf = (size_t)(m0 + (t >> 3)) * K + gcolA;
  const int gsw = ((t & 3) ^ ((t >> 2) & 3)) * 8;
  const size_t baseB = (size_t)(n0 + (t >> 2)) * K + gsw;
  const int ldsoffB = w * 512;

  const int rx = lane & 7;
  const int sA0 = (((2 * slot) ^ rx) << 2);
  const int sA1 = (((2 * slot + 1) ^ rx) << 2);
  const int sB = ((slot ^ (fr & 3)) << 3);

  f32x4 acc[4][8] = {};

#define STAGEA01(tile) { \
    const int _b = (tile) % 3; const size_t _k = (size_t)(tile) * 32; \
    GLL16(A32 + baseAf + _k,                   &smemA[_b][w * 256]); \
    GLL16(A32 + baseAf + (size_t) 64 * K + _k, &smemA[_b][2048 + w * 256]); }
#define STAGEA23(tile) { \
    const int _b = (tile) % 3; const size_t _k = (size_t)(tile) * 32; \
    GLL16(A32 + baseAf + (size_t)128 * K + _k, &smemA[_b][4096 + w * 256]); \
    GLL16(A32 + baseAf + (size_t)192 * K + _k, &smemA[_b][6144 + w * 256]); }
#define STAGEB(tile) { \
    const int _b = (tile) % 3; const size_t _k = (size_t)(tile) * 32; \
    GLL16(Bw + baseB + _k,                  &smemB[_b][ldsoffB]); \
    GLL16(Bw + baseB + (size_t)128 * K + _k, &smemB[_b][4096 + ldsoffB]); }
#define BPAIR(n0i) \
    b0 = *reinterpret_cast<const bf16x8*>(Bt + (wn * 128 + (n0i) * 16 + fr) * 32 + sB); \
    b1 = *reinterpret_cast<const bf16x8*>(Bt + (wn * 128 + (n0i + 1) * 16 + fr) * 32 + sB);
#define MMAPAIR(n0i) \
    __builtin_amdgcn_s_setprio(1); \
    _Pragma("unroll") \
    for (int mi = 0; mi < 4; ++mi) { \
      acc[mi][n0i]     = __builtin_amdgcn_mfma_f32_16x16x32_bf16(afr[mi], b0, acc[mi][n0i], 0, 0, 0); \
      acc[mi][n0i + 1] = __builtin_amdgcn_mfma_f32_16x16x32_bf16(afr[mi], b1, acc[mi][n0i + 1], 0, 0, 0); \
    } \
    __builtin_amdgcn_s_setprio(0);

  // prologue: tiles 0,1 in flight (A4+B2 each); drain tile 0 (6 left)
  STAGEA01(0); STAGEA23(0); STAGEB(0);
  STAGEA01(1); STAGEA23(1); STAGEB(1);
  asm volatile("s_waitcnt vmcnt(6)" ::: "memory");
  __builtin_amdgcn_s_barrier();
  __builtin_amdgcn_sched_barrier(0);

  for (int p = 0; p < NT; ++p) {
    const float*  At = &smemA[p % 3][0];
    const ushort* Bt = &smemB[p % 3][0];
    const bool stg = (p + 2 < NT);       // block-uniform
    bf16x8 afr[4], b0, b1;
    // ---- sub-phase 0: all A frags + B pair 0 + stage A(p+2) slabs 0,1
#pragma unroll
    for (int mi = 0; mi < 4; ++mi) {
      const float* rbase = At + (wm * 64 + mi * 16 + fr) * 32;
      f32x4 a0 = *reinterpret_cast<const f32x4*>(rbase + sA0);
      f32x4 a1 = *reinterpret_cast<const f32x4*>(rbase + sA1);
      uint4 uu;
      asm("v_cvt_pk_bf16_f32 %0, %1, %2" : "=v"(uu.x) : "v"(a0[0]), "v"(a0[1]));
      asm("v_cvt_pk_bf16_f32 %0, %1, %2" : "=v"(uu.y) : "v"(a0[2]), "v"(a0[3]));
      asm("v_cvt_pk_bf16_f32 %0, %1, %2" : "=v"(uu.z) : "v"(a1[0]), "v"(a1[1]));
      asm("v_cvt_pk_bf16_f32 %0, %1, %2" : "=v"(uu.w) : "v"(a1[2]), "v"(a1[3]));
      afr[mi] = *reinterpret_cast<bf16x8*>(&uu);
    }
    BPAIR(0);
    if (stg) STAGEA01(p + 2);
    __builtin_amdgcn_s_barrier();
    MMAPAIR(0);
    // ---- sub-phase 1: B pair 1 + stage A(p+2) slabs 2,3
    BPAIR(2);
    if (stg) STAGEA23(p + 2);
    __builtin_amdgcn_s_barrier();
    MMAPAIR(2);
    // ---- sub-phase 2: B pair 2 + stage B(p+2)
    BPAIR(4);
    if (stg) STAGEB(p + 2);
    __builtin_amdgcn_s_barrier();
    MMAPAIR(4);
    // ---- sub-phase 3: B pair 3
    BPAIR(6);
    __builtin_amdgcn_s_barrier();
    MMAPAIR(6);
    // ---- tile end: guarantee tile p+1 resident
    if (p < NT - 1) {
      if (p < NT - 2) asm volatile("s_waitcnt vmcnt(6)" ::: "memory");
      else            asm volatile("s_waitcnt vmcnt(0)" ::: "memory");
      __builtin_amdgcn_s_barrier();
      __builtin_amdgcn_sched_barrier(0);
    }
  }
#undef MMAPAIR
#undef BPAIR
#undef STAGEB
#undef STAGEA23
#undef STAGEA01

  const int fq = (lane >> 4) * 4;
  float bvv[8];
#pragma unroll
  for (int ni = 0; ni < 8; ++ni) bvv[ni] = bias[n0 + wn * 128 + ni * 16 + fr];
#pragma unroll
  for (int mi = 0; mi < 4; ++mi) {
#pragma unroll
    for (int ni = 0; ni < 8; ++ni) {
      const int c = n0 + wn * 128 + ni * 16 + fr;
#pragma unroll
      for (int q = 0; q < 4; ++q) {
        const int r = m0 + wm * 64 + mi * 16 + fq + q;
        float v = acc[mi][ni][q] + bvv[ni];
        if (do_elu) v = (v > 0.f) ? (v + 1.f) : __expf(v);
        Cout[(size_t)r * N + c] = f2bf(v);
      }
    }
  }
}

// ---------------- KV partials + in-block cross-wave reduce (R15 proven):
// 8 slabs; each wave computes 128 s-rows (2 tiles), parks its 64x64 fp32
// partial in its OWN dead KL/VL slices, 256 threads sum 4 waves -> 1 slab.
__global__ __launch_bounds__(256) void kv_kernel(
    const ushort* __restrict__ Kp, const ushort* __restrict__ Vp,
    float* __restrict__ KVpart, float* __restrict__ Kspart) {
  __shared__ ushort KL[4][64][64];
  __shared__ ushort VL[4][64][64];
  __shared__ float REDK[4][64];
  const int bh = blockIdx.x;
  const int chunk = blockIdx.y;
  const int b = bh >> 4, h = bh & 15;
  const int t = threadIdx.x;
  const int w = t >> 6, lane = t & 63;
  const int d0 = (lane >> 2) * 4;
  const int e0 = (lane & 3) * 16;
  const int srow = lane >> 3;
  const int scol = (lane & 7) * 8;

  float acc[4][16] = {};
  float ks[4] = {};

  ushort* lk = &KL[w][0][0];
  ushort* lv = &VL[w][0][0];
  const int s_wave = chunk * 512 + w * 128;

  for (int tile = 0; tile < 2; ++tile) {
    const int s0 = s_wave + tile * 64;
    const size_t gbase = (size_t)(b * SS + s0 + srow) * DM + h * 64 + scol;
    asm volatile("s_waitcnt lgkmcnt(0)" ::: "memory");
#pragma unroll
    for (int it = 0; it < 8; ++it) {
      GLL16(Kp + gbase + (size_t)it * 8 * DM, lk + it * 512);
      GLL16(Vp + gbase + (size_t)it * 8 * DM, lv + it * 512);
    }
    asm volatile("s_waitcnt vmcnt(0)" ::: "memory");
    __builtin_amdgcn_sched_barrier(0);

#pragma unroll 2
    for (int s = 0; s < 64; ++s) {
      float kf[4], vf[16];
      uint2 uk = *reinterpret_cast<const uint2*>(&KL[w][s][d0]);
      uint4 uv0 = *reinterpret_cast<const uint4*>(&VL[w][s][e0]);
      uint4 uv1 = *reinterpret_cast<const uint4*>(&VL[w][s][e0 + 8]);
      unpack4(uk, kf);
      unpack8(uv0, vf);
      unpack8(uv1, vf + 8);
#pragma unroll
      for (int i = 0; i < 4; ++i) {
        ks[i] += kf[i];
#pragma unroll
        for (int j = 0; j < 16; ++j) acc[i][j] += kf[i] * vf[j];
      }
    }
  }

  float* rl = reinterpret_cast<float*>(&KL[w][0][0]);
  float* rh = reinterpret_cast<float*>(&VL[w][0][0]);
#pragma unroll
  for (int i = 0; i < 4; ++i) {
    const int d = d0 + i;
    float* dst = (d < 32) ? (rl + d * 64 + e0) : (rh + (d - 32) * 64 + e0);
#pragma unroll
    for (int j4 = 0; j4 < 4; ++j4) {
      float4 v = { acc[i][j4*4+0], acc[i][j4*4+1], acc[i][j4*4+2], acc[i][j4*4+3] };
      *reinterpret_cast<float4*>(dst + j4 * 4) = v;
    }
  }
  if ((lane & 3) == 0) {
    float4 v = { ks[0], ks[1], ks[2], ks[3] };
    *reinterpret_cast<float4*>(&REDK[w][d0]) = v;
  }
  __syncthreads();

  float* KLf = reinterpret_cast<float*>(&KL[0][0][0]);
  float* VLf = reinterpret_cast<float*>(&VL[0][0][0]);
  float* out = KVpart + ((size_t)chunk * 64 + bh) * 4096;
  for (int e = t; e < 4096; e += 256) {
    const int d = e >> 6;
    const float* bp = (d < 32) ? KLf : VLf;
    const int off = (d < 32) ? e : (e - 2048);
    out[e] = bp[off] + bp[2048 + off] + bp[4096 + off] + bp[6144 + off];
  }
  if (t < 64) {
    Kspart[((size_t)chunk * 64 + bh) * 64 + t] =
        REDK[0][t] + REDK[1][t] + REDK[2][t] + REDK[3][t];
  }
}

// ---------------- reduce 8 partials -> KVTx bf16 [bh][80][64]:
// rows 0..63 = KV^T, row 64 = Ksum, rows 65..79 zeroed here.
__global__ __launch_bounds__(256) void kvreduce_kernel(
    const float* __restrict__ KVpart, const float* __restrict__ Kspart,
    ushort* __restrict__ KVTx) {
  const int idx = blockIdx.x * 256 + threadIdx.x;
  const int bh = idx >> 12;
  const int d = (idx >> 6) & 63;
  const int e = idx & 63;
  float s = 0.f;
#pragma unroll
  for (int c = 0; c < 8; ++c) s += KVpart[(size_t)c * (64 * 4096) + idx];
  KVTx[(size_t)bh * 5120 + e * 64 + d] = f2bf(s);
  if (idx < 64 * 64) {
    float s2 = 0.f;
#pragma unroll
    for (int c = 0; c < 8; ++c) s2 += Kspart[(size_t)c * 4096 + idx];
    KVTx[(size_t)(idx >> 6) * 5120 + 4096 + (idx & 63)] = f2bf(s2);
  }
  if (idx < 64 * 960) {
    const int bh2 = idx / 960;
    const int rem = idx % 960;
    KVTx[(size_t)bh2 * 5120 + 4160 + rem] = 0;
  }
}

// ---------------- Z via MFMA: per (bh, 128-row tile). 4 waves x 32 rows.
__global__ __launch_bounds__(256) void z_mfma_kernel(
    const ushort* __restrict__ Qp, const ushort* __restrict__ KVTx,
    ushort* __restrict__ Zn) {
  const int bh = blockIdx.y;
  const int b = bh >> 4, h = bh & 15;
  const int t = threadIdx.x;
  const int w = t >> 6, lane = t & 63;
  const int fr = lane & 15;
  const int kq = (lane >> 4) * 8;
  const int s0 = blockIdx.x * 128 + w * 32;

  const ushort* kvb = KVTx + (size_t)bh * 5120;
  bf16x8 bfrag[5][2];
#pragma unroll
  for (int ni = 0; ni < 5; ++ni)
#pragma unroll
    for (int ks = 0; ks < 2; ++ks)
      bfrag[ni][ks] = *reinterpret_cast<const bf16x8*>(kvb + (ni * 16 + fr) * 64 + ks * 32 + kq);

  f32x4 acc[2][5] = {};
  const size_t arow = (size_t)(b * SS + s0 + fr) * DM + h * 64;
#pragma unroll
  for (int mi = 0; mi < 2; ++mi) {
#pragma unroll
    for (int ks = 0; ks < 2; ++ks) {
      bf16x8 a = *reinterpret_cast<const bf16x8*>(Qp + arow + (size_t)mi * 16 * DM + ks * 32 + kq);
#pragma unroll
      for (int ni = 0; ni < 5; ++ni)
        acc[mi][ni] = __builtin_amdgcn_mfma_f32_16x16x32_bf16(a, bfrag[ni][ks], acc[mi][ni], 0, 0, 0);
    }
  }

#pragma unroll
  for (int mi = 0; mi < 2; ++mi) {
#pragma unroll
    for (int q = 0; q < 4; ++q) {
      const float dv = __shfl(acc[mi][4][q], lane & 48);
      const float inv = 1.f / (dv + 1e-6f);
      const int r = s0 + mi * 16 + (lane >> 4) * 4 + q;
      ushort* orow = Zn + (size_t)(b * SS + r) * DM + h * 64;
#pragma unroll
      for (int ni = 0; ni < 4; ++ni)
        orow[ni * 16 + fr] = f2bf(acc[mi][ni][q] * inv);
    }
  }
}

extern "C" void kernel_launch(void* const* d_in, const int* in_sizes, int n_in,
                              void* d_out, int out_size, void* d_ws, size_t ws_size,
                              hipStream_t stream) {
  const float* query = (const float*)d_in[0];
  const float* key_  = (const float*)d_in[1];
  const float* value = (const float*)d_in[2];
  const float* w_q = (const float*)d_in[3];
  const float* b_q = (const float*)d_in[4];
  const float* w_k = (const float*)d_in[5];
  const float* b_k = (const float*)d_in[6];
  const float* w_v = (const float*)d_in[7];
  const float* b_v = (const float*)d_in[8];
  const float* w_o = (const float*)d_in[9];
  const float* b_o = (const float*)d_in[10];

  char* ws = (char*)d_ws;
  const size_t NX = (size_t)MM * DM;            // 16,777,216
  ushort* Wq = (ushort*)ws; ws += (size_t)DM * DM * 2;
  ushort* Wk = (ushort*)ws; ws += (size_t)DM * DM * 2;
  ushort* Wv = (ushort*)ws; ws += (size_t)DM * DM * 2;
  ushort* Wo = (ushort*)ws; ws += (size_t)DM * DM * 2;
  ushort* Qp = (ushort*)ws; ws += NX * 2;
  ushort* Kp = (ushort*)ws; ws += NX * 2;
  ushort* Vp = (ushort*)ws; ws += NX * 2;
  float*  KVpart = (float*)ws; ws += (size_t)8 * 64 * 4096 * 4;   // 8 MiB
  float*  Kspart = (float*)ws; ws += (size_t)8 * 4096 * 4;        // 128 KiB
  ushort* KVTx = (ushort*)ws; ws += (size_t)64 * 80 * 64 * 2;     // 640 KiB
  ushort* Zn = (ushort*)ws; ws += NX * 2;

  cast_w4<<<4 * 1024, 256, 0, stream>>>(w_q, w_k, w_v, w_o, Wq, Wk, Wv, Wo);

  dim3 gg3(DM / 256, MM / 256, 3);   // (4, 64, 3): fused projections
  gemm8pa<<<gg3, 512, 0, stream>>>(query, key_, value, Wq, Wk, Wv,
                                   b_q, b_k, b_v, Qp, Kp, Vp);

  kv_kernel<<<dim3(64, 8), 256, 0, stream>>>(Kp, Vp, KVpart, Kspart);
  kvreduce_kernel<<<1024, 256, 0, stream>>>(KVpart, Kspart, KVTx);
  z_mfma_kernel<<<dim3(32, 64), 256, 0, stream>>>(Qp, KVTx, Zn);

  dim3 gg(DM / 256, MM / 256);   // (4, 64)
  gemm8p<2><<<gg, 512, 0, stream>>>(Zn, Wo, b_o, d_out);
}

// Round 18
// 254.192 us; speedup vs baseline: 1.1322x; 1.1322x over previous
//
#include <hip/hip_runtime.h>
#include <stdint.h>

#define DM 1024
#define NH 16
#define DKH 64
#define BB 4
#define SS 4096
#define MM (BB*SS)   // 16384

typedef __bf16 bf16x8 __attribute__((ext_vector_type(8)));
typedef float f32x4 __attribute__((ext_vector_type(4)));

__device__ __forceinline__ float bf2f(ushort u) {
  union { uint32_t i; float f; } v; v.i = ((uint32_t)u) << 16; return v.f;
}
__device__ __forceinline__ ushort f2bf(float f) {
  union { float f; uint32_t i; } v; v.f = f;
  uint32_t x = v.i;
  uint32_t r = (x + 0x7fffu + ((x >> 16) & 1u)) >> 16;
  return (ushort)r;
}
__device__ __forceinline__ void unpack8(uint4 u, float* o) {
  o[0] = bf2f((ushort)(u.x & 0xffff)); o[1] = bf2f((ushort)(u.x >> 16));
  o[2] = bf2f((ushort)(u.y & 0xffff)); o[3] = bf2f((ushort)(u.y >> 16));
  o[4] = bf2f((ushort)(u.z & 0xffff)); o[5] = bf2f((ushort)(u.z >> 16));
  o[6] = bf2f((ushort)(u.w & 0xffff)); o[7] = bf2f((ushort)(u.w >> 16));
}
__device__ __forceinline__ void unpack4(uint2 u, float* o) {
  o[0] = bf2f((ushort)(u.x & 0xffff)); o[1] = bf2f((ushort)(u.x >> 16));
  o[2] = bf2f((ushort)(u.y & 0xffff)); o[3] = bf2f((ushort)(u.y >> 16));
}

#define GLL16(g, l) __builtin_amdgcn_global_load_lds( \
    (__attribute__((address_space(1))) void*)(g), \
    (__attribute__((address_space(3))) void*)(l), 16, 0, 0)

// ---------------- fused cast: 4 weight matrices in one launch ----------------
__global__ void cast_w4(const float* __restrict__ s0, const float* __restrict__ s1,
                        const float* __restrict__ s2, const float* __restrict__ s3,
                        ushort* __restrict__ d0, ushort* __restrict__ d1,
                        ushort* __restrict__ d2, ushort* __restrict__ d3) {
  const int which = blockIdx.x >> 10;              // 1024 blocks per tensor
  const int i = ((blockIdx.x & 1023) * 256 + threadIdx.x) * 4;
  const float* src = which == 0 ? s0 : (which == 1 ? s1 : (which == 2 ? s2 : s3));
  ushort* dst = which == 0 ? d0 : (which == 1 ? d1 : (which == 2 ? d2 : d3));
  float4 v = *reinterpret_cast<const float4*>(src + i);
  ushort4 o; o.x = f2bf(v.x); o.y = f2bf(v.y); o.z = f2bf(v.z); o.w = f2bf(v.w);
  *reinterpret_cast<ushort4*>(dst + i) = o;
}

// ---------------- 256x256 counted-vmcnt pipelined bf16 GEMM (bf16 A) ----------------
// R7's proven kernel, used for the final output projection.
template<int MODE>
__global__ __launch_bounds__(512, 2) void gemm8p(
    const ushort* __restrict__ A, const ushort* __restrict__ Bw,
    const float* __restrict__ bias, void* __restrict__ Cout) {
  constexpr int K = DM, N = DM;
  constexpr int NT = K / 32;
  __shared__ ushort smem[4][2][256 * 32];   // 128 KiB
  const int t = threadIdx.x;
  const int lane = t & 63;
  const int w = t >> 6;
  const int id = blockIdx.y * gridDim.x + blockIdx.x;
  const int cpx = (gridDim.x * gridDim.y) >> 3;
  const int swz = (id & 7) * cpx + (id >> 3);
  const int bx = swz % gridDim.x;
  const int by = swz / gridDim.x;
  const int m0 = by * 256, n0 = bx * 256;
  const int wm = w >> 2, wn = w & 3;
  const int fr = lane & 15;
  const int slot = lane >> 4;

  const int gsw = ((t & 3) ^ ((t >> 2) & 3)) * 8;
  const size_t baseA = (size_t)(m0 + (t >> 2)) * K + gsw;
  const size_t baseB = (size_t)(n0 + (t >> 2)) * K + gsw;
  const int ldsoff = w * 512;

  f32x4 acc[8][4] = {};

#define STAGE(tile) { \
    const int _b = (tile) & 3; const size_t _k = (size_t)(tile) * 32; \
    GLL16(A + baseA + _k, &smem[_b][0][ldsoff]); \
    GLL16(A + baseA + (size_t)128 * K + _k, &smem[_b][0][4096 + ldsoff]); \
    GLL16(Bw + baseB + _k, &smem[_b][1][ldsoff]); \
    GLL16(Bw + baseB + (size_t)128 * K + _k, &smem[_b][1][4096 + ldsoff]); }

  STAGE(0); STAGE(1); STAGE(2);
  asm volatile("s_waitcnt vmcnt(8)" ::: "memory");
  __builtin_amdgcn_s_barrier();
  __builtin_amdgcn_sched_barrier(0);

  for (int p = 0; p < NT; ++p) {
    const ushort* At = &smem[p & 3][0][0];
    const ushort* Bt = &smem[p & 3][1][0];
    bf16x8 bfr[4], afr[8];
#pragma unroll
    for (int ni = 0; ni < 4; ++ni) {
      const int row = wn * 64 + ni * 16 + fr;
      bfr[ni] = *reinterpret_cast<const bf16x8*>(Bt + row * 32 + ((slot ^ (fr & 3)) << 3));
    }
#pragma unroll
    for (int mi = 0; mi < 8; ++mi) {
      const int row = wm * 128 + mi * 16 + fr;
      afr[mi] = *reinterpret_cast<const bf16x8*>(At + row * 32 + ((slot ^ (fr & 3)) << 3));
    }
    if (p + 3 < NT) STAGE(p + 3);
    __builtin_amdgcn_s_setprio(1);
#pragma unroll
    for (int mi = 0; mi < 8; ++mi)
#pragma unroll
      for (int ni = 0; ni < 4; ++ni)
        acc[mi][ni] = __builtin_amdgcn_mfma_f32_16x16x32_bf16(afr[mi], bfr[ni], acc[mi][ni], 0, 0, 0);
    __builtin_amdgcn_s_setprio(0);
    if (p < NT - 1) {
      if (p < NT - 3)       asm volatile("s_waitcnt vmcnt(8)" ::: "memory");
      else if (p == NT - 3) asm volatile("s_waitcnt vmcnt(4)" ::: "memory");
      else                  asm volatile("s_waitcnt vmcnt(0)" ::: "memory");
      __builtin_amdgcn_s_barrier();
      __builtin_amdgcn_sched_barrier(0);
    }
  }
#undef STAGE

  const int fq = (lane >> 4) * 4;
  float bv[4];
#pragma unroll
  for (int ni = 0; ni < 4; ++ni) bv[ni] = bias[n0 + wn * 64 + ni * 16 + fr];
#pragma unroll
  for (int mi = 0; mi < 8; ++mi) {
#pragma unroll
    for (int ni = 0; ni < 4; ++ni) {
      const int c = n0 + wn * 64 + ni * 16 + fr;
#pragma unroll
      for (int q = 0; q < 4; ++q) {
        const int r = m0 + wm * 128 + mi * 16 + fq + q;
        float v = acc[mi][ni][q] + bv[ni];
        if constexpr (MODE == 0) v = (v > 0.f) ? (v + 1.f) : __expf(v);
        if constexpr (MODE == 2) {
          reinterpret_cast<float*>(Cout)[(size_t)r * N + c] = v;
        } else {
          reinterpret_cast<ushort*>(Cout)[(size_t)r * N + c] = f2bf(v);
        }
      }
    }
  }
}

// ---------------- fused-cast projection GEMM (R10 v3, verbatim — best known):
// all 3 projections in ONE launch (blockIdx.z), A fp32 staged raw via
// global_load_lds (depth-3), read-side v_cvt_pk_bf16_f32, B via GLL16 depth-3.
// Wave tile 64x128.  Steady vmcnt(6).  Staged-byte-rate-bound (~11 B/cy/CU);
// schedule variants R8/R11/R13/R14/R17 all regressed — frozen.
__global__ __launch_bounds__(512, 2) void gemm8pa(
    const float* __restrict__ Q32, const float* __restrict__ K32,
    const float* __restrict__ V32,
    const ushort* __restrict__ Wq, const ushort* __restrict__ Wk,
    const ushort* __restrict__ Wv,
    const float* __restrict__ bq, const float* __restrict__ bk,
    const float* __restrict__ bv_,
    ushort* __restrict__ Qp, ushort* __restrict__ Kp, ushort* __restrict__ Vp) {
  constexpr int K = DM, N = DM;
  constexpr int NT = K / 32;            // 32
  __shared__ float  smemA[3][256 * 32];   // 96 KiB (fp32 tiles)
  __shared__ ushort smemB[3][256 * 32];   // 48 KiB
  const int bz = blockIdx.z;
  const float*  A32  = bz == 0 ? Q32 : (bz == 1 ? K32 : V32);
  const ushort* Bw   = bz == 0 ? Wq  : (bz == 1 ? Wk  : Wv);
  const float*  bias = bz == 0 ? bq  : (bz == 1 ? bk  : bv_);
  ushort*       Cout = bz == 0 ? Qp  : (bz == 1 ? Kp  : Vp);
  const bool do_elu = (bz != 2);

  const int t = threadIdx.x;
  const int lane = t & 63;
  const int w = t >> 6;
  const int id = blockIdx.y * gridDim.x + blockIdx.x;
  const int cpx = (gridDim.x * gridDim.y) >> 3;
  const int swz = (id & 7) * cpx + (id >> 3);
  const int bx = swz % gridDim.x;
  const int by = swz / gridDim.x;
  const int m0 = by * 256, n0 = bx * 256;
  const int wm = w >> 1, wn = w & 1;      // wave tile: 64 rows x 128 cols
  const int fr = lane & 15;
  const int slot = lane >> 4;

  const int gcolA = (((t & 7) ^ ((t >> 3) & 7)) << 2);
  const size_t baseAf = (size_t)(m0 + (t >> 3)) * K + gcolA;
  const int gsw = ((t & 3) ^ ((t >> 2) & 3)) * 8;
  const size_t baseB = (size_t)(n0 + (t >> 2)) * K + gsw;
  const int ldsoffB = w * 512;

  const int rx = lane & 7;
  const int sA0 = (((2 * slot) ^ rx) << 2);
  const int sA1 = (((2 * slot + 1) ^ rx) << 2);
  const int sB = ((slot ^ (fr & 3)) << 3);

  f32x4 acc[4][8] = {};

#define STAGEA(tile) { \
    const int _b = (tile) % 3; const size_t _k = (size_t)(tile) * 32; \
    GLL16(A32 + baseAf + _k,                      &smemA[_b][w * 256]); \
    GLL16(A32 + baseAf + (size_t) 64 * K + _k,    &smemA[_b][2048 + w * 256]); \
    GLL16(A32 + baseAf + (size_t)128 * K + _k,    &smemA[_b][4096 + w * 256]); \
    GLL16(A32 + baseAf + (size_t)192 * K + _k,    &smemA[_b][6144 + w * 256]); }
#define STAGEB(tile) { \
    const int _b = (tile) % 3; const size_t _k = (size_t)(tile) * 32; \
    GLL16(Bw + baseB + _k,                  &smemB[_b][ldsoffB]); \
    GLL16(Bw + baseB + (size_t)128 * K + _k, &smemB[_b][4096 + ldsoffB]); }

  STAGEA(0); STAGEB(0); STAGEA(1); STAGEB(1);
  asm volatile("s_waitcnt vmcnt(6)" ::: "memory");
  __builtin_amdgcn_s_barrier();
  __builtin_amdgcn_sched_barrier(0);

  for (int p = 0; p < NT; ++p) {
    const float*  At = &smemA[p % 3][0];
    const ushort* Bt = &smemB[p % 3][0];
    bf16x8 bfr[8], afr[4];
#pragma unroll
    for (int ni = 0; ni < 8; ++ni) {
      const int row = wn * 128 + ni * 16 + fr;
      bfr[ni] = *reinterpret_cast<const bf16x8*>(Bt + row * 32 + sB);
    }
#pragma unroll
    for (int mi = 0; mi < 4; ++mi) {
      const float* rbase = At + (wm * 64 + mi * 16 + fr) * 32;
      f32x4 a0 = *reinterpret_cast<const f32x4*>(rbase + sA0);
      f32x4 a1 = *reinterpret_cast<const f32x4*>(rbase + sA1);
      uint4 uu;
      asm("v_cvt_pk_bf16_f32 %0, %1, %2" : "=v"(uu.x) : "v"(a0[0]), "v"(a0[1]));
      asm("v_cvt_pk_bf16_f32 %0, %1, %2" : "=v"(uu.y) : "v"(a0[2]), "v"(a0[3]));
      asm("v_cvt_pk_bf16_f32 %0, %1, %2" : "=v"(uu.z) : "v"(a1[0]), "v"(a1[1]));
      asm("v_cvt_pk_bf16_f32 %0, %1, %2" : "=v"(uu.w) : "v"(a1[2]), "v"(a1[3]));
      afr[mi] = *reinterpret_cast<bf16x8*>(&uu);
    }
    if (p + 2 < NT) { STAGEA(p + 2); STAGEB(p + 2); }
    __builtin_amdgcn_s_setprio(1);
#pragma unroll
    for (int mi = 0; mi < 4; ++mi)
#pragma unroll
      for (int ni = 0; ni < 8; ++ni)
        acc[mi][ni] = __builtin_amdgcn_mfma_f32_16x16x32_bf16(afr[mi], bfr[ni], acc[mi][ni], 0, 0, 0);
    __builtin_amdgcn_s_setprio(0);
    if (p < NT - 1) {
      if (p < NT - 2) asm volatile("s_waitcnt vmcnt(6)" ::: "memory");
      else            asm volatile("s_waitcnt vmcnt(0)" ::: "memory");
      __builtin_amdgcn_s_barrier();
      __builtin_amdgcn_sched_barrier(0);
    }
  }
#undef STAGEA
#undef STAGEB

  const int fq = (lane >> 4) * 4;
  float bvv[8];
#pragma unroll
  for (int ni = 0; ni < 8; ++ni) bvv[ni] = bias[n0 + wn * 128 + ni * 16 + fr];
#pragma unroll
  for (int mi = 0; mi < 4; ++mi) {
#pragma unroll
    for (int ni = 0; ni < 8; ++ni) {
      const int c = n0 + wn * 128 + ni * 16 + fr;
#pragma unroll
      for (int q = 0; q < 4; ++q) {
        const int r = m0 + wm * 64 + mi * 16 + fq + q;
        float v = acc[mi][ni][q] + bvv[ni];
        if (do_elu) v = (v > 0.f) ? (v + 1.f) : __expf(v);
        Cout[(size_t)r * N + c] = f2bf(v);
      }
    }
  }
}

// ---------------- KV partials + in-block cross-wave reduce (R15 proven):
// 8 slabs; each wave computes 128 s-rows (2 tiles), parks its 64x64 fp32
// partial in its OWN dead KL/VL slices, 256 threads sum 4 waves -> 1 slab.
__global__ __launch_bounds__(256) void kv_kernel(
    const ushort* __restrict__ Kp, const ushort* __restrict__ Vp,
    float* __restrict__ KVpart, float* __restrict__ Kspart) {
  __shared__ ushort KL[4][64][64];
  __shared__ ushort VL[4][64][64];
  __shared__ float REDK[4][64];
  const int bh = blockIdx.x;
  const int chunk = blockIdx.y;
  const int b = bh >> 4, h = bh & 15;
  const int t = threadIdx.x;
  const int w = t >> 6, lane = t & 63;
  const int d0 = (lane >> 2) * 4;
  const int e0 = (lane & 3) * 16;
  const int srow = lane >> 3;
  const int scol = (lane & 7) * 8;

  float acc[4][16] = {};
  float ks[4] = {};

  ushort* lk = &KL[w][0][0];
  ushort* lv = &VL[w][0][0];
  const int s_wave = chunk * 512 + w * 128;

  for (int tile = 0; tile < 2; ++tile) {
    const int s0 = s_wave + tile * 64;
    const size_t gbase = (size_t)(b * SS + s0 + srow) * DM + h * 64 + scol;
    asm volatile("s_waitcnt lgkmcnt(0)" ::: "memory");
#pragma unroll
    for (int it = 0; it < 8; ++it) {
      GLL16(Kp + gbase + (size_t)it * 8 * DM, lk + it * 512);
      GLL16(Vp + gbase + (size_t)it * 8 * DM, lv + it * 512);
    }
    asm volatile("s_waitcnt vmcnt(0)" ::: "memory");
    __builtin_amdgcn_sched_barrier(0);

#pragma unroll 2
    for (int s = 0; s < 64; ++s) {
      float kf[4], vf[16];
      uint2 uk = *reinterpret_cast<const uint2*>(&KL[w][s][d0]);
      uint4 uv0 = *reinterpret_cast<const uint4*>(&VL[w][s][e0]);
      uint4 uv1 = *reinterpret_cast<const uint4*>(&VL[w][s][e0 + 8]);
      unpack4(uk, kf);
      unpack8(uv0, vf);
      unpack8(uv1, vf + 8);
#pragma unroll
      for (int i = 0; i < 4; ++i) {
        ks[i] += kf[i];
#pragma unroll
        for (int j = 0; j < 16; ++j) acc[i][j] += kf[i] * vf[j];
      }
    }
  }

  float* rl = reinterpret_cast<float*>(&KL[w][0][0]);
  float* rh = reinterpret_cast<float*>(&VL[w][0][0]);
#pragma unroll
  for (int i = 0; i < 4; ++i) {
    const int d = d0 + i;
    float* dst = (d < 32) ? (rl + d * 64 + e0) : (rh + (d - 32) * 64 + e0);
#pragma unroll
    for (int j4 = 0; j4 < 4; ++j4) {
      float4 v = { acc[i][j4*4+0], acc[i][j4*4+1], acc[i][j4*4+2], acc[i][j4*4+3] };
      *reinterpret_cast<float4*>(dst + j4 * 4) = v;
    }
  }
  if ((lane & 3) == 0) {
    float4 v = { ks[0], ks[1], ks[2], ks[3] };
    *reinterpret_cast<float4*>(&REDK[w][d0]) = v;
  }
  __syncthreads();

  float* KLf = reinterpret_cast<float*>(&KL[0][0][0]);
  float* VLf = reinterpret_cast<float*>(&VL[0][0][0]);
  float* out = KVpart + ((size_t)chunk * 64 + bh) * 4096;
  for (int e = t; e < 4096; e += 256) {
    const int d = e >> 6;
    const float* bp = (d < 32) ? KLf : VLf;
    const int off = (d < 32) ? e : (e - 2048);
    out[e] = bp[off] + bp[2048 + off] + bp[4096 + off] + bp[6144 + off];
  }
  if (t < 64) {
    Kspart[((size_t)chunk * 64 + bh) * 64 + t] =
        REDK[0][t] + REDK[1][t] + REDK[2][t] + REDK[3][t];
  }
}

// ---------------- reduce 8 partials -> KVTx bf16 [bh][80][64]:
// rows 0..63 = KV^T, row 64 = Ksum, rows 65..79 zeroed here.
__global__ __launch_bounds__(256) void kvreduce_kernel(
    const float* __restrict__ KVpart, const float* __restrict__ Kspart,
    ushort* __restrict__ KVTx) {
  const int idx = blockIdx.x * 256 + threadIdx.x;
  const int bh = idx >> 12;
  const int d = (idx >> 6) & 63;
  const int e = idx & 63;
  float s = 0.f;
#pragma unroll
  for (int c = 0; c < 8; ++c) s += KVpart[(size_t)c * (64 * 4096) + idx];
  KVTx[(size_t)bh * 5120 + e * 64 + d] = f2bf(s);
  if (idx < 64 * 64) {
    float s2 = 0.f;
#pragma unroll
    for (int c = 0; c < 8; ++c) s2 += Kspart[(size_t)c * 4096 + idx];
    KVTx[(size_t)(idx >> 6) * 5120 + 4096 + (idx & 63)] = f2bf(s2);
  }
  if (idx < 64 * 960) {
    const int bh2 = idx / 960;
    const int rem = idx % 960;
    KVTx[(size_t)bh2 * 5120 + 4160 + rem] = 0;
  }
}

// ---------------- Z via MFMA: per (bh, 128-row tile). 4 waves x 32 rows.
__global__ __launch_bounds__(256) void z_mfma_kernel(
    const ushort* __restrict__ Qp, const ushort* __restrict__ KVTx,
    ushort* __restrict__ Zn) {
  const int bh = blockIdx.y;
  const int b = bh >> 4, h = bh & 15;
  const int t = threadIdx.x;
  const int w = t >> 6, lane = t & 63;
  const int fr = lane & 15;
  const int kq = (lane >> 4) * 8;
  const int s0 = blockIdx.x * 128 + w * 32;

  const ushort* kvb = KVTx + (size_t)bh * 5120;
  bf16x8 bfrag[5][2];
#pragma unroll
  for (int ni = 0; ni < 5; ++ni)
#pragma unroll
    for (int ks = 0; ks < 2; ++ks)
      bfrag[ni][ks] = *reinterpret_cast<const bf16x8*>(kvb + (ni * 16 + fr) * 64 + ks * 32 + kq);

  f32x4 acc[2][5] = {};
  const size_t arow = (size_t)(b * SS + s0 + fr) * DM + h * 64;
#pragma unroll
  for (int mi = 0; mi < 2; ++mi) {
#pragma unroll
    for (int ks = 0; ks < 2; ++ks) {
      bf16x8 a = *reinterpret_cast<const bf16x8*>(Qp + arow + (size_t)mi * 16 * DM + ks * 32 + kq);
#pragma unroll
      for (int ni = 0; ni < 5; ++ni)
        acc[mi][ni] = __builtin_amdgcn_mfma_f32_16x16x32_bf16(a, bfrag[ni][ks], acc[mi][ni], 0, 0, 0);
    }
  }

#pragma unroll
  for (int mi = 0; mi < 2; ++mi) {
#pragma unroll
    for (int q = 0; q < 4; ++q) {
      const float dv = __shfl(acc[mi][4][q], lane & 48);
      const float inv = 1.f / (dv + 1e-6f);
      const int r = s0 + mi * 16 + (lane >> 4) * 4 + q;
      ushort* orow = Zn + (size_t)(b * SS + r) * DM + h * 64;
#pragma unroll
      for (int ni = 0; ni < 4; ++ni)
        orow[ni * 16 + fr] = f2bf(acc[mi][ni][q] * inv);
    }
  }
}

extern "C" void kernel_launch(void* const* d_in, const int* in_sizes, int n_in,
                              void* d_out, int out_size, void* d_ws, size_t ws_size,
                              hipStream_t stream) {
  const float* query = (const float*)d_in[0];
  const float* key_  = (const float*)d_in[1];
  const float* value = (const float*)d_in[2];
  const float* w_q = (const float*)d_in[3];
  const float* b_q = (const float*)d_in[4];
  const float* w_k = (const float*)d_in[5];
  const float* b_k = (const float*)d_in[6];
  const float* w_v = (const float*)d_in[7];
  const float* b_v = (const float*)d_in[8];
  const float* w_o = (const float*)d_in[9];
  const float* b_o = (const float*)d_in[10];

  char* ws = (char*)d_ws;
  const size_t NX = (size_t)MM * DM;            // 16,777,216
  ushort* Wq = (ushort*)ws; ws += (size_t)DM * DM * 2;
  ushort* Wk = (ushort*)ws; ws += (size_t)DM * DM * 2;
  ushort* Wv = (ushort*)ws; ws += (size_t)DM * DM * 2;
  ushort* Wo = (ushort*)ws; ws += (size_t)DM * DM * 2;
  ushort* Qp = (ushort*)ws; ws += NX * 2;
  ushort* Kp = (ushort*)ws; ws += NX * 2;
  ushort* Vp = (ushort*)ws; ws += NX * 2;
  float*  KVpart = (float*)ws; ws += (size_t)8 * 64 * 4096 * 4;   // 8 MiB
  float*  Kspart = (float*)ws; ws += (size_t)8 * 4096 * 4;        // 128 KiB
  ushort* KVTx = (ushort*)ws; ws += (size_t)64 * 80 * 64 * 2;     // 640 KiB
  ushort* Zn = (ushort*)ws; ws += NX * 2;

  cast_w4<<<4 * 1024, 256, 0, stream>>>(w_q, w_k, w_v, w_o, Wq, Wk, Wv, Wo);

  dim3 gg3(DM / 256, MM / 256, 3);   // (4, 64, 3): fused projections (R10 v3)
  gemm8pa<<<gg3, 512, 0, stream>>>(query, key_, value, Wq, Wk, Wv,
                                   b_q, b_k, b_v, Qp, Kp, Vp);

  kv_kernel<<<dim3(64, 8), 256, 0, stream>>>(Kp, Vp, KVpart, Kspart);
  kvreduce_kernel<<<1024, 256, 0, stream>>>(KVpart, Kspart, KVTx);
  z_mfma_kernel<<<dim3(32, 64), 256, 0, stream>>>(Qp, KVTx, Zn);

  dim3 gg(DM / 256, MM / 256);   // (4, 64)
  gemm8p<2><<<gg, 512, 0, stream>>>(Zn, Wo, b_o, d_out);
}